// Round 2
// baseline (34551.868 us; speedup 1.0000x reference)
//
#include <hip/hip_runtime.h>
#include <math.h>

#define NB 256
#define NT 4096
#define NH 128

#define DWL_OFF (NB*NT)            // 1048576
#define OUT_OFF (NB*NT + NB*2)     // 1049088

// fast transcendentals: v_exp_f32 + v_rcp_f32 (~1e-6 rel err, fine vs 2e-3 tolerance)
__device__ __forceinline__ float fexp2_(float x) { return __builtin_amdgcn_exp2f(x); }
__device__ __forceinline__ float frcp_(float x)  { return __builtin_amdgcn_rcpf(x); }
__device__ __forceinline__ float fsig_(float v)  { return frcp_(1.0f + fexp2_(v * -1.44269504f)); }
// tanh(x) = 1 - 2/(1+exp2(2x*log2e)); saturates correctly at +-inf
__device__ __forceinline__ float ftanh_(float v) { return 1.0f - 2.0f * frcp_(1.0f + fexp2_(v * 2.88539008f)); }

__launch_bounds__(1024, 4)
__global__ void drnn_fused(const float* __restrict__ x,
                           const float* __restrict__ W0in,
                           const float* __restrict__ h0,
                           const float* __restrict__ dnn_w0, const float* __restrict__ dnn_b0,
                           const float* __restrict__ dnn_w1, const float* __restrict__ dnn_b1,
                           const float* __restrict__ dnn_w2, const float* __restrict__ dnn_b2,
                           const float* __restrict__ gru_w_ih, const float* __restrict__ gru_w_hh,
                           const float* __restrict__ gru_b_ih, const float* __restrict__ gru_b_hh,
                           const float* __restrict__ fc_w, const float* __restrict__ scaling,
                           float* __restrict__ out)
{
    __shared__ float xb[NT * 3];        // 48 KB: x[b,:,:] staged once
    __shared__ float sh_h[2][NH];       // ping-pong hidden state
    __shared__ float sh_a0[NH];
    __shared__ float sh_a1[NH];
    __shared__ float sh_rg[NH];
    __shared__ float sh_zg[NH];
    __shared__ float sh_gni[NH];
    __shared__ float sh_gnh[NH];
    __shared__ float sh_W[2];

    const int tid  = threadIdx.x;
    const int lane = tid & 63;
    const int b    = blockIdx.x;

    // ---- stage x[b] into LDS (12288 floats = 3072 float4, coalesced) ----
    {
        const float4* src = (const float4*)(x + (size_t)b * (NT * 3));
        float4* dst = (float4*)xb;
        #pragma unroll
        for (int i = 0; i < 3; ++i) dst[tid + i * 1024] = src[tid + i * 1024];
    }

    // ---- HALF-row of the big weight matrix in VGPRs (64 floats/thread, no spill) ----
    // tid <  256 : dnn_w1   row (tid>>1),        half (tid&1)
    // tid >= 256 : gru_w_hh row ((tid-256)>>1),  half (tid&1)
    const int isD  = (tid < 256);
    const int g    = isD ? tid : (tid - 256);
    const int row  = g >> 1;
    const int half = g & 1;

    float wreg[64];
    {
        const float* srcw = isD ? (dnn_w1 + (size_t)row * NH + half * 64)
                                : (gru_w_hh + (size_t)row * NH + half * 64);
        #pragma unroll
        for (int k = 0; k < 64; k += 4) {
            float4 v = *(const float4*)(srcw + k);
            wreg[k] = v.x; wreg[k + 1] = v.y; wreg[k + 2] = v.z; wreg[k + 3] = v.w;
        }
    }

    // ---- small per-role weights ----
    float w0a0 = 0, w0a1 = 0, w0a2 = 0, w0a3 = 0;
    float w0b0 = 0, w0b1 = 0, w0b2 = 0, w0b3 = 0;
    float b0a = 0, b0b = 0, b1r = 0;
    float wih0 = 0, wih1 = 0, bihr = 0, bhhr = 0;
    if (isD) {
        const int r0 = 2 * lane, r1 = 2 * lane + 1;   // a0 rows (each D wave covers all 128)
        w0a0 = dnn_w0[r0 * 4 + 0]; w0a1 = dnn_w0[r0 * 4 + 1];
        w0a2 = dnn_w0[r0 * 4 + 2]; w0a3 = dnn_w0[r0 * 4 + 3];
        w0b0 = dnn_w0[r1 * 4 + 0]; w0b1 = dnn_w0[r1 * 4 + 1];
        w0b2 = dnn_w0[r1 * 4 + 2]; w0b3 = dnn_w0[r1 * 4 + 3];
        b0a = dnn_b0[r0]; b0b = dnn_b0[r1];
        b1r = dnn_b1[row];
    } else {
        wih0 = gru_w_ih[row * 2 + 0]; wih1 = gru_w_ih[row * 2 + 1];
        bihr = gru_b_ih[row]; bhhr = gru_b_hh[row];
    }

    // per-lane slices for the wave-redundant reductions
    const float w2_0a = dnn_w2[2 * lane],      w2_0b = dnn_w2[2 * lane + 1];
    const float w2_1a = dnn_w2[NH + 2 * lane], w2_1b = dnn_w2[NH + 2 * lane + 1];
    const float b2_0  = dnn_b2[0],             b2_1  = dnn_b2[1];
    const float fc0a  = fc_w[2 * lane],        fc0b  = fc_w[2 * lane + 1];
    const float fc1a  = fc_w[NH + 2 * lane],   fc1b  = fc_w[NH + 2 * lane + 1];
    const float sc0   = scaling[0],            sc1   = scaling[1];

    if (tid < 128) sh_h[0][tid] = h0[(size_t)b * NH + tid];
    if (tid == 0) { sh_W[0] = W0in[b * 2]; sh_W[1] = W0in[b * 2 + 1]; }
    __syncthreads();

    const int hoff = half << 6;   // 0 or 64: which half of the activation vector we consume

    for (int t = 0; t < NT; ++t) {
        const float* hin = sh_h[t & 1];
        float* hout      = sh_h[(t + 1) & 1];
        float gh = 0.0f;

        // ---------------- phase A: dnn a0->a1 (D) || gh half-matvec (G) ----------------
        if (isD) {
            const float i0 = sh_W[0], i1 = sh_W[1];
            const float i2 = xb[t * 3 + 1], i3 = xb[t * 3 + 2];
            float a0a = fmaf(w0a0, i0, fmaf(w0a1, i1, fmaf(w0a2, i2, fmaf(w0a3, i3, b0a))));
            float a0b = fmaf(w0b0, i0, fmaf(w0b1, i1, fmaf(w0b2, i2, fmaf(w0b3, i3, b0b))));
            // each of the 4 D waves writes all 128 a0 (2/lane); redundant writes identical
            sh_a0[2 * lane]     = fmaxf(a0a, 0.0f);
            sh_a0[2 * lane + 1] = fmaxf(a0b, 0.0f);
            asm volatile("s_waitcnt lgkmcnt(0)" ::: "memory");  // same-wave LDS RAW ordering
            const float* base = sh_a0 + hoff;
            float ac0 = 0.f, ac1 = 0.f, ac2 = 0.f, ac3 = 0.f;
            #pragma unroll
            for (int k = 0; k < 64; k += 4) {
                const float4 v = *(const float4*)(base + k);    // 2 addrs/wave -> free 2-way
                ac0 = fmaf(wreg[k + 0], v.x, ac0);
                ac1 = fmaf(wreg[k + 1], v.y, ac1);
                ac2 = fmaf(wreg[k + 2], v.z, ac2);
                ac3 = fmaf(wreg[k + 3], v.w, ac3);
            }
            float s = (ac0 + ac1) + (ac2 + ac3);
            s += __shfl_xor(s, 1);                              // combine the two halves
            if (!half) sh_a1[row] = fmaxf(s + b1r, 0.0f);
        } else {
            const float* base = hin + hoff;
            float ac0 = 0.f, ac1 = 0.f, ac2 = 0.f, ac3 = 0.f;
            #pragma unroll
            for (int k = 0; k < 64; k += 4) {
                const float4 v = *(const float4*)(base + k);
                ac0 = fmaf(wreg[k + 0], v.x, ac0);
                ac1 = fmaf(wreg[k + 1], v.y, ac1);
                ac2 = fmaf(wreg[k + 2], v.z, ac2);
                ac3 = fmaf(wreg[k + 3], v.w, ac3);
            }
            float s = (ac0 + ac1) + (ac2 + ac3);
            s += __shfl_xor(s, 1);                              // full row dot in both halves
            gh = s + bhhr;                                      // carried across B1 in reg
        }
        __syncthreads();   // B1: a1 ready

        // ---------------- phase B: xt reduce (per-G-wave redundant) + gates ----------------
        if (!isD) {
            const float pa = sh_a1[2 * lane], pb = sh_a1[2 * lane + 1];
            float s0 = fmaf(w2_0a, pa, w2_0b * pb);
            float s1 = fmaf(w2_1a, pa, w2_1b * pb);
            #pragma unroll
            for (int off = 32; off; off >>= 1) {
                s0 += __shfl_xor(s0, off);
                s1 += __shfl_xor(s1, off);
            }
            const float xt0 = s0 + b2_0, xt1 = s1 + b2_1;
            const float gi = fmaf(wih0, xt0, fmaf(wih1, xt1, bihr));
            if (!half) {
                if (row < 128)      sh_rg[row]        = fsig_(gi + gh);
                else if (row < 256) sh_zg[row - 128]  = fsig_(gi + gh);
                else              { sh_gni[row - 256] = gi; sh_gnh[row - 256] = gh; }
            }
        }
        __syncthreads();   // B2: gates ready

        // ---------------- phase C: wave 0 computes h' + dW reduce + outputs ----------------
        if (tid < 64) {
            const int j0 = 2 * lane, j1 = 2 * lane + 1;
            const float rg0 = sh_rg[j0], zg0 = sh_zg[j0], gni0 = sh_gni[j0], gnh0 = sh_gnh[j0], hv0 = hin[j0];
            const float rg1 = sh_rg[j1], zg1 = sh_zg[j1], gni1 = sh_gni[j1], gnh1 = sh_gnh[j1], hv1 = hin[j1];
            const float ng0 = ftanh_(fmaf(rg0, gnh0, gni0));
            const float ng1 = ftanh_(fmaf(rg1, gnh1, gni1));
            const float hn0 = fmaf(zg0, hv0 - ng0, ng0);   // (1-z)*n + z*h
            const float hn1 = fmaf(zg1, hv1 - ng1, ng1);
            hout[j0] = hn0; hout[j1] = hn1;
            float p0 = fmaf(fc0a, hn0, fc0b * hn1);
            float p1 = fmaf(fc1a, hn0, fc1b * hn1);
            #pragma unroll
            for (int off = 32; off; off >>= 1) {
                p0 += __shfl_xor(p0, off);
                p1 += __shfl_xor(p1, off);
            }
            const float dW0 = p0 * sc0, dW1 = p1 * sc1;
            const float W0n = sh_W[0] + dW0, W1n = sh_W[1] + dW1;
            if (lane == 0) {
                sh_W[0] = W0n; sh_W[1] = W1n;
                out[(size_t)b * NT + t] = fsig_(fmaf(W0n, xb[t * 3], W1n));
                float* op = out + OUT_OFF + ((size_t)b * NT + t) * 2;
                op[0] = W0n; op[1] = W1n;
                if (t == NT - 1) {
                    out[DWL_OFF + b * 2 + 0] = dW0;
                    out[DWL_OFF + b * 2 + 1] = dW1;
                }
            }
        }
        __syncthreads();   // B3: h', W ready for next step
    }
}

extern "C" void kernel_launch(void* const* d_in, const int* in_sizes, int n_in,
                              void* d_out, int out_size, void* d_ws, size_t ws_size,
                              hipStream_t stream) {
    (void)in_sizes; (void)n_in; (void)out_size; (void)d_ws; (void)ws_size;
    const float* x        = (const float*)d_in[0];
    const float* W0in     = (const float*)d_in[1];
    const float* h0       = (const float*)d_in[2];
    const float* dnn_w0   = (const float*)d_in[3];
    const float* dnn_b0   = (const float*)d_in[4];
    const float* dnn_w1   = (const float*)d_in[5];
    const float* dnn_b1   = (const float*)d_in[6];
    const float* dnn_w2   = (const float*)d_in[7];
    const float* dnn_b2   = (const float*)d_in[8];
    const float* gru_w_ih = (const float*)d_in[9];
    const float* gru_w_hh = (const float*)d_in[10];
    const float* gru_b_ih = (const float*)d_in[11];
    const float* gru_b_hh = (const float*)d_in[12];
    const float* fc_w     = (const float*)d_in[13];
    const float* scaling  = (const float*)d_in[14];
    float* out = (float*)d_out;

    drnn_fused<<<NB, 1024, 0, stream>>>(x, W0in, h0, dnn_w0, dnn_b0, dnn_w1, dnn_b1,
                                        dnn_w2, dnn_b2, gru_w_ih, gru_w_hh, gru_b_ih,
                                        gru_b_hh, fc_w, scaling, out);
}

// Round 4
// 6892.888 us; speedup vs baseline: 5.0127x; 5.0127x over previous
//
#include <hip/hip_runtime.h>
#include <math.h>

#define NB 256
#define NT 4096
#define NH 128

#define DWL_OFF (NB*NT)            // 1048576
#define OUT_OFF (NB*NT + NB*2)     // 1049088

// fast transcendentals: v_exp_f32 + v_rcp_f32 (~1e-6 rel err, fine vs 2e-3 tolerance)
__device__ __forceinline__ float fexp2_(float x) { return __builtin_amdgcn_exp2f(x); }
__device__ __forceinline__ float frcp_(float x)  { return __builtin_amdgcn_rcpf(x); }
__device__ __forceinline__ float fsig_(float v)  { return frcp_(1.0f + fexp2_(v * -1.44269504f)); }
// tanh(x) = 1 - 2/(1+exp2(2x*log2e)); saturates correctly at +-inf
__device__ __forceinline__ float ftanh_(float v) { return 1.0f - 2.0f * frcp_(1.0f + fexp2_(v * 2.88539008f)); }

// 2nd launch_bounds arg behaves as CUDA min-BLOCKS-per-CU on this toolchain
// (R1: (512,2)->cap 128 VGPR; R2: (1024,4)->cap 64 VGPR — both decoded exactly).
// (512,1) -> 1 block/CU -> 8 waves/CU -> 256-VGPR budget: wreg[128]+working fits.
__launch_bounds__(512, 1)
__global__ void drnn_fused(const float* __restrict__ x,
                           const float* __restrict__ W0in,
                           const float* __restrict__ h0,
                           const float* __restrict__ dnn_w0, const float* __restrict__ dnn_b0,
                           const float* __restrict__ dnn_w1, const float* __restrict__ dnn_b1,
                           const float* __restrict__ dnn_w2, const float* __restrict__ dnn_b2,
                           const float* __restrict__ gru_w_ih, const float* __restrict__ gru_w_hh,
                           const float* __restrict__ gru_b_ih, const float* __restrict__ gru_b_hh,
                           const float* __restrict__ fc_w, const float* __restrict__ scaling,
                           float* __restrict__ out)
{
    __shared__ float xb[NT * 3];        // 48 KB: x[b,:,:] staged once
    __shared__ float sh_h[2][NH];       // ping-pong hidden state
    __shared__ float sh_a0[NH];
    __shared__ float sh_a1[NH];
    __shared__ float sh_rg[NH];
    __shared__ float sh_zg[NH];
    __shared__ float sh_gni[NH];
    __shared__ float sh_gnh[NH];
    __shared__ float sh_W[2];

    const int tid  = threadIdx.x;
    const int lane = tid & 63;
    const int wav  = tid >> 6;
    const int b    = blockIdx.x;

    // ---- stage x[b] into LDS (12288 floats = 3072 float4, coalesced) ----
    {
        const float4* src = (const float4*)(x + (size_t)b * (NT * 3));
        float4* dst = (float4*)xb;
        #pragma unroll
        for (int i = 0; i < 6; ++i) dst[tid + i * 512] = src[tid + i * 512];
    }

    // ---- big weight row in VGPRs: dnn_w1 row (tid<128) or gru_w_hh row (tid>=128) ----
    float wreg[128];
    {
        const float* srcw = (tid < 128) ? (dnn_w1 + (size_t)tid * NH)
                                        : (gru_w_hh + (size_t)(tid - 128) * NH);
        #pragma unroll
        for (int k = 0; k < 128; k += 4) {
            float4 v = *(const float4*)(srcw + k);
            wreg[k] = v.x; wreg[k + 1] = v.y; wreg[k + 2] = v.z; wreg[k + 3] = v.w;
        }
    }

    // ---- small per-role weights ----
    float w0a0 = 0, w0a1 = 0, w0a2 = 0, w0a3 = 0;
    float w0b0 = 0, w0b1 = 0, w0b2 = 0, w0b3 = 0;
    float b0a = 0, b0b = 0, b1r = 0;
    float wih0 = 0, wih1 = 0, bihr = 0, bhhr = 0;
    if (tid < 128) {
        const int r0 = 2 * lane, r1 = 2 * lane + 1;   // a0 rows, wave-redundant in waves 0,1
        w0a0 = dnn_w0[r0 * 4 + 0]; w0a1 = dnn_w0[r0 * 4 + 1];
        w0a2 = dnn_w0[r0 * 4 + 2]; w0a3 = dnn_w0[r0 * 4 + 3];
        w0b0 = dnn_w0[r1 * 4 + 0]; w0b1 = dnn_w0[r1 * 4 + 1];
        w0b2 = dnn_w0[r1 * 4 + 2]; w0b3 = dnn_w0[r1 * 4 + 3];
        b0a = dnn_b0[r0]; b0b = dnn_b0[r1];
        b1r = dnn_b1[tid];
    } else {
        const int r = tid - 128;
        wih0 = gru_w_ih[r * 2 + 0]; wih1 = gru_w_ih[r * 2 + 1];
        bihr = gru_b_ih[r]; bhhr = gru_b_hh[r];
    }

    // per-lane slices for the wave-redundant reductions (all threads)
    const float w2_0a = dnn_w2[2 * lane],      w2_0b = dnn_w2[2 * lane + 1];
    const float w2_1a = dnn_w2[NH + 2 * lane], w2_1b = dnn_w2[NH + 2 * lane + 1];
    const float b2_0  = dnn_b2[0],             b2_1  = dnn_b2[1];
    const float fc0a  = fc_w[2 * lane],        fc0b  = fc_w[2 * lane + 1];
    const float fc1a  = fc_w[NH + 2 * lane],   fc1b  = fc_w[NH + 2 * lane + 1];
    const float sc0   = scaling[0],            sc1   = scaling[1];

    if (tid < 128) sh_h[0][tid] = h0[(size_t)b * NH + tid];
    if (tid == 0) { sh_W[0] = W0in[b * 2]; sh_W[1] = W0in[b * 2 + 1]; }
    __syncthreads();

    for (int t = 0; t < NT; ++t) {
        const float* hin = sh_h[t & 1];
        float* hout      = sh_h[(t + 1) & 1];
        float gh = 0.0f;

        // ---------------- phase A: dnn a0->a1 (D) || gh matvec (G) ----------------
        if (tid < 128) {
            const float i0 = sh_W[0], i1 = sh_W[1];
            const float i2 = xb[t * 3 + 1], i3 = xb[t * 3 + 2];
            float a0a = fmaf(w0a0, i0, fmaf(w0a1, i1, fmaf(w0a2, i2, fmaf(w0a3, i3, b0a))));
            float a0b = fmaf(w0b0, i0, fmaf(w0b1, i1, fmaf(w0b2, i2, fmaf(w0b3, i3, b0b))));
            // each D wave writes ALL 128 a0 values (2 per lane) -> no cross-wave dep;
            // redundant writes from waves 0,1 are bitwise identical (benign race)
            sh_a0[2 * lane]     = fmaxf(a0a, 0.0f);
            sh_a0[2 * lane + 1] = fmaxf(a0b, 0.0f);
            asm volatile("s_waitcnt lgkmcnt(0)" ::: "memory");  // same-wave LDS RAW ordering
            float ac0 = 0.f, ac1 = 0.f, ac2 = 0.f, ac3 = 0.f;
            #pragma unroll
            for (int k = 0; k < 128; k += 4) {
                const float4 v = *(const float4*)(sh_a0 + k);   // uniform addr -> broadcast
                ac0 = fmaf(wreg[k + 0], v.x, ac0);
                ac1 = fmaf(wreg[k + 1], v.y, ac1);
                ac2 = fmaf(wreg[k + 2], v.z, ac2);
                ac3 = fmaf(wreg[k + 3], v.w, ac3);
            }
            sh_a1[tid] = fmaxf(((ac0 + ac1) + (ac2 + ac3)) + b1r, 0.0f);
        } else {
            float ac0 = 0.f, ac1 = 0.f, ac2 = 0.f, ac3 = 0.f;
            #pragma unroll
            for (int k = 0; k < 128; k += 4) {
                const float4 v = *(const float4*)(hin + k);     // uniform addr -> broadcast
                ac0 = fmaf(wreg[k + 0], v.x, ac0);
                ac1 = fmaf(wreg[k + 1], v.y, ac1);
                ac2 = fmaf(wreg[k + 2], v.z, ac2);
                ac3 = fmaf(wreg[k + 3], v.w, ac3);
            }
            gh = ((ac0 + ac1) + (ac2 + ac3)) + bhhr;            // carried across B1 in reg
        }
        __syncthreads();   // B1: a1 ready

        // ---------------- phase B: xt reduce (per-G-wave redundant) + gates ----------------
        if (tid >= 128) {
            const float2 pv = *(const float2*)(sh_a1 + 2 * lane);
            float s0 = fmaf(w2_0a, pv.x, w2_0b * pv.y);
            float s1 = fmaf(w2_1a, pv.x, w2_1b * pv.y);
            #pragma unroll
            for (int off = 32; off; off >>= 1) {
                s0 += __shfl_xor(s0, off);
                s1 += __shfl_xor(s1, off);
            }
            const float xt0 = s0 + b2_0, xt1 = s1 + b2_1;
            const float gi = fmaf(wih0, xt0, fmaf(wih1, xt1, bihr));
            const int r = tid - 128;
            if (r < 128)      sh_rg[r]        = fsig_(gi + gh);
            else if (r < 256) sh_zg[r - 128]  = fsig_(gi + gh);
            else            { sh_gni[r - 256] = gi; sh_gnh[r - 256] = gh; }
        }
        __syncthreads();   // B2: gates ready

        // ---------------- phase C: wave 0 computes h' + dW reduce + outputs ----------------
        if (tid < 64) {
            const int j0 = 2 * lane;
            const float2 rg  = *(const float2*)(sh_rg  + j0);
            const float2 zg  = *(const float2*)(sh_zg  + j0);
            const float2 gni = *(const float2*)(sh_gni + j0);
            const float2 gnh = *(const float2*)(sh_gnh + j0);
            const float2 hv  = *(const float2*)(hin    + j0);
            const float ng0 = ftanh_(fmaf(rg.x, gnh.x, gni.x));
            const float ng1 = ftanh_(fmaf(rg.y, gnh.y, gni.y));
            const float hn0 = fmaf(zg.x, hv.x - ng0, ng0);   // (1-z)*n + z*h
            const float hn1 = fmaf(zg.y, hv.y - ng1, ng1);
            *(float2*)(hout + j0) = make_float2(hn0, hn1);
            float p0 = fmaf(fc0a, hn0, fc0b * hn1);
            float p1 = fmaf(fc1a, hn0, fc1b * hn1);
            #pragma unroll
            for (int off = 32; off; off >>= 1) {
                p0 += __shfl_xor(p0, off);
                p1 += __shfl_xor(p1, off);
            }
            const float dW0 = p0 * sc0, dW1 = p1 * sc1;
            const float W0n = sh_W[0] + dW0, W1n = sh_W[1] + dW1;
            if (lane == 0) {
                sh_W[0] = W0n; sh_W[1] = W1n;
                out[(size_t)b * NT + t] = fsig_(fmaf(W0n, xb[t * 3], W1n));
                float* op = out + OUT_OFF + ((size_t)b * NT + t) * 2;
                op[0] = W0n; op[1] = W1n;
                if (t == NT - 1) {
                    out[DWL_OFF + b * 2 + 0] = dW0;
                    out[DWL_OFF + b * 2 + 1] = dW1;
                }
            }
        }
        __syncthreads();   // B3: h', W ready for next step
    }
}

extern "C" void kernel_launch(void* const* d_in, const int* in_sizes, int n_in,
                              void* d_out, int out_size, void* d_ws, size_t ws_size,
                              hipStream_t stream) {
    (void)in_sizes; (void)n_in; (void)out_size; (void)d_ws; (void)ws_size;
    const float* x        = (const float*)d_in[0];
    const float* W0in     = (const float*)d_in[1];
    const float* h0       = (const float*)d_in[2];
    const float* dnn_w0   = (const float*)d_in[3];
    const float* dnn_b0   = (const float*)d_in[4];
    const float* dnn_w1   = (const float*)d_in[5];
    const float* dnn_b1   = (const float*)d_in[6];
    const float* dnn_w2   = (const float*)d_in[7];
    const float* dnn_b2   = (const float*)d_in[8];
    const float* gru_w_ih = (const float*)d_in[9];
    const float* gru_w_hh = (const float*)d_in[10];
    const float* gru_b_ih = (const float*)d_in[11];
    const float* gru_b_hh = (const float*)d_in[12];
    const float* fc_w     = (const float*)d_in[13];
    const float* scaling  = (const float*)d_in[14];
    float* out = (float*)d_out;

    drnn_fused<<<NB, 512, 0, stream>>>(x, W0in, h0, dnn_w0, dnn_b0, dnn_w1, dnn_b1,
                                       dnn_w2, dnn_b2, gru_w_ih, gru_w_hh, gru_b_ih,
                                       gru_b_hh, fc_w, scaling, out);
}